// Round 2
// baseline (252.776 us; speedup 1.0000x reference)
//
#include <hip/hip_runtime.h>
#include <math.h>

#define NROWS 4096
#define DDIM  256
#define BM 64
#define BN 64
#define BK 64
#define LDSPAD 4   // stride 68 floats: keeps ds_read_b128 16B-aligned, <=2-way read conflicts

// ---------------- Kernel 1: L2-normalize rows + positive dots ----------------
// 1 wave per row (64 lanes x float4 = 256 elems). Block = 4 waves = 4 rows.
__global__ __launch_bounds__(256) void normalize_kernel(
    const float* __restrict__ emb_i, const float* __restrict__ emb_j,
    float* __restrict__ zi, float* __restrict__ zj, float* __restrict__ pos)
{
    const int wave = threadIdx.x >> 6;
    const int lane = threadIdx.x & 63;
    const int row  = blockIdx.x * 4 + wave;

    const float4 vi = *((const float4*)(emb_i + (size_t)row * DDIM) + lane);
    const float4 vj = *((const float4*)(emb_j + (size_t)row * DDIM) + lane);

    float ssi = vi.x*vi.x + vi.y*vi.y + vi.z*vi.z + vi.w*vi.w;
    float ssj = vj.x*vj.x + vj.y*vj.y + vj.z*vj.z + vj.w*vj.w;
    #pragma unroll
    for (int m = 1; m < 64; m <<= 1) {
        ssi += __shfl_xor(ssi, m);
        ssj += __shfl_xor(ssj, m);
    }
    const float ri = 1.0f / fmaxf(sqrtf(ssi), 1e-12f);
    const float rj = 1.0f / fmaxf(sqrtf(ssj), 1e-12f);

    float4 zvi = { vi.x*ri, vi.y*ri, vi.z*ri, vi.w*ri };
    float4 zvj = { vj.x*rj, vj.y*rj, vj.z*rj, vj.w*rj };
    *((float4*)(zi + (size_t)row * DDIM) + lane) = zvi;
    *((float4*)(zj + (size_t)row * DDIM) + lane) = zvj;

    float p = zvi.x*zvj.x + zvi.y*zvj.y + zvi.z*zvj.z + zvi.w*zvj.w;
    #pragma unroll
    for (int m = 1; m < 64; m <<= 1) p += __shfl_xor(p, m);
    if (lane == 0) pos[row] = p;
}

// ---------- Kernel 2: fused S = Zi*Zj^T tile, exp, row/col partial sums ----------
// 64x64 tile per block, 256 threads (16x16), 4x4 register blocking.
// LDS is k-major (As[k][m]) so the inner loop does two ds_read_b128 per k.
__global__ __launch_bounds__(256) void gemm_fused_kernel(
    const float* __restrict__ zi, const float* __restrict__ zj,
    float* __restrict__ rowsum, float* __restrict__ colsum)
{
    __shared__ float As[BK][BM + LDSPAD];
    __shared__ float Bs[BK][BN + LDSPAD];

    const int bm = blockIdx.x * BM;
    const int bn = blockIdx.y * BN;
    const int tx = threadIdx.x & 15;   // 0..15
    const int ty = threadIdx.x >> 4;   // 0..15

    float acc[4][4] = {};

    const int lr = threadIdx.x >> 4;        // staging row within 16-row stripe
    const int lc = (threadIdx.x & 15) * 4;  // staging col (float4)

    for (int k0 = 0; k0 < DDIM; k0 += BK) {
        #pragma unroll
        for (int rr = 0; rr < BM; rr += 16) {
            const int r = rr + lr;
            float4 va = *(const float4*)(zi + (size_t)(bm + r) * DDIM + k0 + lc);
            As[lc + 0][r] = va.x; As[lc + 1][r] = va.y;
            As[lc + 2][r] = va.z; As[lc + 3][r] = va.w;
            float4 vb = *(const float4*)(zj + (size_t)(bn + r) * DDIM + k0 + lc);
            Bs[lc + 0][r] = vb.x; Bs[lc + 1][r] = vb.y;
            Bs[lc + 2][r] = vb.z; Bs[lc + 3][r] = vb.w;
        }
        __syncthreads();

        #pragma unroll 16
        for (int k = 0; k < BK; ++k) {
            const float4 a = *(const float4*)&As[k][ty * 4];
            const float4 b = *(const float4*)&Bs[k][tx * 4];
            const float av[4] = { a.x, a.y, a.z, a.w };
            const float bv[4] = { b.x, b.y, b.z, b.w };
            #pragma unroll
            for (int mi = 0; mi < 4; ++mi)
                #pragma unroll
                for (int ni = 0; ni < 4; ++ni)
                    acc[mi][ni] = fmaf(av[mi], bv[ni], acc[mi][ni]);
        }
        __syncthreads();
    }

    // Epilogue: e = exp(sim / 0.5) = exp(2*sim); accumulate row & col sums.
    float rp[4] = {0.f, 0.f, 0.f, 0.f};
    float cp[4] = {0.f, 0.f, 0.f, 0.f};
    #pragma unroll
    for (int mi = 0; mi < 4; ++mi)
        #pragma unroll
        for (int ni = 0; ni < 4; ++ni) {
            const float e = __expf(2.0f * acc[mi][ni]);
            rp[mi] += e;
            cp[ni] += e;
        }

    // Row sums: reduce across tx (lane bits 0..3). lane = (ty&3)*16 + tx.
    #pragma unroll
    for (int m = 1; m < 16; m <<= 1)
        #pragma unroll
        for (int mi = 0; mi < 4; ++mi) rp[mi] += __shfl_xor(rp[mi], m);
    if (tx == 0) {
        #pragma unroll
        for (int mi = 0; mi < 4; ++mi)
            atomicAdd(&rowsum[bm + ty * 4 + mi], rp[mi]);
    }

    // Col sums: reduce across ty-within-wave (lane bits 4,5), 4 atomics/col/block.
    #pragma unroll
    for (int ni = 0; ni < 4; ++ni) {
        cp[ni] += __shfl_xor(cp[ni], 16);
        cp[ni] += __shfl_xor(cp[ni], 32);
    }
    if ((ty & 3) == 0) {
        #pragma unroll
        for (int ni = 0; ni < 4; ++ni)
            atomicAdd(&colsum[bn + tx * 4 + ni], cp[ni]);
    }
}

// ---------------- Kernel 3: final loss reduction ----------------
__global__ __launch_bounds__(256) void finalize_kernel(
    const float* __restrict__ pos, const float* __restrict__ rowsum,
    const float* __restrict__ colsum, float* __restrict__ out)
{
    float s = 0.0f;
    for (int r = threadIdx.x; r < NROWS; r += 256) {
        s += -4.0f * pos[r] + logf(0.5f * rowsum[r]) + logf(0.5f * colsum[r]);
    }
    __shared__ float part[4];
    #pragma unroll
    for (int m = 1; m < 64; m <<= 1) s += __shfl_xor(s, m);
    if ((threadIdx.x & 63) == 0) part[threadIdx.x >> 6] = s;
    __syncthreads();
    if (threadIdx.x == 0)
        out[0] = (part[0] + part[1] + part[2] + part[3]) / (2.0f * NROWS);
}

extern "C" void kernel_launch(void* const* d_in, const int* in_sizes, int n_in,
                              void* d_out, int out_size, void* d_ws, size_t ws_size,
                              hipStream_t stream)
{
    const float* emb_i = (const float*)d_in[0];
    const float* emb_j = (const float*)d_in[1];

    float* ws      = (float*)d_ws;
    float* zi      = ws;                         // N*D
    float* zj      = zi + (size_t)NROWS * DDIM;  // N*D
    float* pos     = zj + (size_t)NROWS * DDIM;  // N
    float* rowsum  = pos + NROWS;                // N
    float* colsum  = rowsum + NROWS;             // N

    // d_ws is poisoned 0xAA before every timed launch — zero the accumulators.
    hipMemsetAsync(rowsum, 0, 2 * NROWS * sizeof(float), stream);

    normalize_kernel<<<NROWS / 4, 256, 0, stream>>>(emb_i, emb_j, zi, zj, pos);

    dim3 grid(NROWS / BM, NROWS / BN);
    gemm_fused_kernel<<<grid, 256, 0, stream>>>(zi, zj, rowsum, colsum);

    finalize_kernel<<<1, 256, 0, stream>>>(pos, rowsum, colsum, (float*)d_out);
}

// Round 3
// 87.412 us; speedup vs baseline: 2.8918x; 2.8918x over previous
//
#include <hip/hip_runtime.h>
#include <math.h>

#define NROWS 4096
#define DDIM  256
#define BM 128
#define BN 128
#define BK 64
#define LOG2E2 2.8853900817779268f   // 2*log2(e): exp(2S) = exp2(LOG2E2 * S)

typedef __attribute__((ext_vector_type(8))) short short8;  // 8 bf16 (4 VGPRs)
typedef __attribute__((ext_vector_type(4))) float f32x4;   // MFMA 16x16 C/D

__device__ __forceinline__ unsigned short f2bf(float f) {  // RNE float->bf16
    unsigned int u = __float_as_uint(f);
    u += 0x7fffu + ((u >> 16) & 1u);
    return (unsigned short)(u >> 16);
}

__device__ __forceinline__ float exp2_fast(float x) {
#if __has_builtin(__builtin_amdgcn_exp2f)
    return __builtin_amdgcn_exp2f(x);
#else
    return exp2f(x);
#endif
}

// global -> LDS direct DMA, 16B per lane. LDS dest must be wave-uniform base
// (lane offset is implicit +lane*16); global src is per-lane (pre-swizzled).
#define GLOAD_LDS16(gsrc, ldst)                                          \
    __builtin_amdgcn_global_load_lds(                                    \
        (__attribute__((address_space(1))) void*)(gsrc),                 \
        (__attribute__((address_space(3))) void*)(ldst), 16, 0, 0)

// ---------------- Kernel 1: L2-normalize rows + positive dots ----------------
// 1 wave per row. pos computed in fp32 (exact); bf16 copies written for MFMA.
// A-side (zi) pre-scaled by 2*log2(e) so the GEMM accumulator is exp2-ready.
__global__ __launch_bounds__(256) void normalize_kernel(
    const float* __restrict__ emb_i, const float* __restrict__ emb_j,
    unsigned short* __restrict__ zi, unsigned short* __restrict__ zj,
    float* __restrict__ pos)
{
    const int wave = threadIdx.x >> 6;
    const int lane = threadIdx.x & 63;
    const int row  = blockIdx.x * 4 + wave;

    const float4 vi = *((const float4*)(emb_i + (size_t)row * DDIM) + lane);
    const float4 vj = *((const float4*)(emb_j + (size_t)row * DDIM) + lane);

    float ssi = vi.x*vi.x + vi.y*vi.y + vi.z*vi.z + vi.w*vi.w;
    float ssj = vj.x*vj.x + vj.y*vj.y + vj.z*vj.z + vj.w*vj.w;
    #pragma unroll
    for (int m = 1; m < 64; m <<= 1) {
        ssi += __shfl_xor(ssi, m);
        ssj += __shfl_xor(ssj, m);
    }
    const float ri = 1.0f / fmaxf(sqrtf(ssi), 1e-12f);
    const float rj = 1.0f / fmaxf(sqrtf(ssj), 1e-12f);

    const float zix = vi.x*ri, ziy = vi.y*ri, ziz = vi.z*ri, ziw = vi.w*ri;
    const float zjx = vj.x*rj, zjy = vj.y*rj, zjz = vj.z*rj, zjw = vj.w*rj;

    float p = zix*zjx + ziy*zjy + ziz*zjz + ziw*zjw;
    #pragma unroll
    for (int m = 1; m < 64; m <<= 1) p += __shfl_xor(p, m);
    if (lane == 0) pos[row] = p;

    ushort4 oi = { f2bf(zix*LOG2E2), f2bf(ziy*LOG2E2), f2bf(ziz*LOG2E2), f2bf(ziw*LOG2E2) };
    ushort4 oj = { f2bf(zjx), f2bf(zjy), f2bf(zjz), f2bf(zjw) };
    *((ushort4*)(zi + (size_t)row * DDIM) + lane) = oi;
    *((ushort4*)(zj + (size_t)row * DDIM) + lane) = oj;
}

// ---------- Kernel 2: bf16 MFMA S-tile + exp2 + row/col partial sums ----------
// 128x128 tile, 4 waves (2x2), each wave 64x64 = 4x4 frags of 16x16x32 MFMA.
// LDS [128][64] bf16, st-slot XOR swizzle (byte ^= (row&7)<<4) applied on the
// pre-swizzled global source (global_load_lds writes linearly) AND the ds_read.
__global__ __launch_bounds__(256) void gemm_fused_kernel(
    const unsigned short* __restrict__ zi, const unsigned short* __restrict__ zj,
    float* __restrict__ rowsum, float* __restrict__ colsum)
{
    __shared__ unsigned short As[BM * BK];
    __shared__ unsigned short Bs[BM * BK];

    const int tid  = threadIdx.x;
    const int lane = tid & 63;
    const int wave = tid >> 6;
    const int g    = lane >> 4;    // k-group 0..3
    const int fr   = lane & 15;    // fragment row 0..15
    const int wr   = wave >> 1;    // wave row 0..1
    const int wc   = wave & 1;     // wave col 0..1
    const int bm   = blockIdx.x * BM;
    const int bn   = blockIdx.y * BN;

    f32x4 acc[4][4] = {};          // all indices compile-time (rule #20)

    for (int k0 = 0; k0 < DDIM; k0 += BK) {
        // Stage A and B tiles: 4 rounds x 256 lanes x 16B = 16KB each.
        #pragma unroll
        for (int it = 0; it < 4; ++it) {
            const int idx  = it * 256 + tid;
            const int row  = idx >> 3;                       // 0..127
            const int slot = idx & 7;                        // 16B slot in row
            const int soff = ((slot ^ (row & 7)) << 3);      // swizzled src col (ushorts)
            const int loff = (it * 256 + wave * 64) << 3;    // wave-uniform LDS base (ushorts)
            GLOAD_LDS16(zi + (size_t)(bm + row) * DDIM + k0 + soff, As + loff);
            GLOAD_LDS16(zj + (size_t)(bn + row) * DDIM + k0 + soff, Bs + loff);
        }
        __syncthreads();   // drains vmcnt before barrier (compiler-inserted)

        #pragma unroll
        for (int kk = 0; kk < 2; ++kk) {
            short8 a[4], b[4];
            #pragma unroll
            for (int mi = 0; mi < 4; ++mi) {
                const int row  = wr * 64 + mi * 16 + fr;
                const int slot = kk * 4 + g;
                a[mi] = *(const short8*)&As[row * 64 + ((slot ^ (row & 7)) << 3)];
            }
            #pragma unroll
            for (int ni = 0; ni < 4; ++ni) {
                const int row  = wc * 64 + ni * 16 + fr;
                const int slot = kk * 4 + g;
                b[ni] = *(const short8*)&Bs[row * 64 + ((slot ^ (row & 7)) << 3)];
            }
            #pragma unroll
            for (int mi = 0; mi < 4; ++mi)
                #pragma unroll
                for (int ni = 0; ni < 4; ++ni)
                    acc[mi][ni] = __builtin_amdgcn_mfma_f32_16x16x32_bf16(
                        a[mi], b[ni], acc[mi][ni], 0, 0, 0);
        }
        __syncthreads();
    }

    // Epilogue. acc[mi][ni][j] = LOG2E2 * S at row bm+wr*64+mi*16+g*4+j,
    // col bn+wc*64+ni*16+fr (C/D layout: col=lane&15, row=(lane>>4)*4+reg).
    float rp[4][4];                 // [mi][j] row partials
    float cp[4] = {0.f, 0.f, 0.f, 0.f};  // [ni] col partials (col fixed per lane)
    #pragma unroll
    for (int mi = 0; mi < 4; ++mi)
        #pragma unroll
        for (int j = 0; j < 4; ++j) rp[mi][j] = 0.f;

    #pragma unroll
    for (int mi = 0; mi < 4; ++mi)
        #pragma unroll
        for (int ni = 0; ni < 4; ++ni)
            #pragma unroll
            for (int j = 0; j < 4; ++j) {
                const float e = exp2_fast(acc[mi][ni][j]);
                rp[mi][j] += e;
                cp[ni]    += e;
            }

    // Row sums: reduce over cols = lane bits 0..3.
    #pragma unroll
    for (int mi = 0; mi < 4; ++mi)
        #pragma unroll
        for (int j = 0; j < 4; ++j) {
            float v = rp[mi][j];
            v += __shfl_xor(v, 1); v += __shfl_xor(v, 2);
            v += __shfl_xor(v, 4); v += __shfl_xor(v, 8);
            if (fr == 0)
                atomicAdd(&rowsum[bm + wr * 64 + mi * 16 + g * 4 + j], v);
        }

    // Col sums: reduce over row-groups = lane bits 4,5.
    #pragma unroll
    for (int ni = 0; ni < 4; ++ni) {
        float v = cp[ni];
        v += __shfl_xor(v, 16); v += __shfl_xor(v, 32);
        if (g == 0)
            atomicAdd(&colsum[bn + wc * 64 + ni * 16 + fr], v);
    }
}

// ---------------- Kernel 3: final loss reduction ----------------
__global__ __launch_bounds__(256) void finalize_kernel(
    const float* __restrict__ pos, const float* __restrict__ rowsum,
    const float* __restrict__ colsum, float* __restrict__ out)
{
    float s = 0.0f;
    for (int r = threadIdx.x; r < NROWS; r += 256) {
        s += -4.0f * pos[r] + logf(0.5f * rowsum[r]) + logf(0.5f * colsum[r]);
    }
    __shared__ float part[4];
    #pragma unroll
    for (int m = 1; m < 64; m <<= 1) s += __shfl_xor(s, m);
    if ((threadIdx.x & 63) == 0) part[threadIdx.x >> 6] = s;
    __syncthreads();
    if (threadIdx.x == 0)
        out[0] = (part[0] + part[1] + part[2] + part[3]) / (2.0f * NROWS);
}

extern "C" void kernel_launch(void* const* d_in, const int* in_sizes, int n_in,
                              void* d_out, int out_size, void* d_ws, size_t ws_size,
                              hipStream_t stream)
{
    const float* emb_i = (const float*)d_in[0];
    const float* emb_j = (const float*)d_in[1];

    unsigned short* zi = (unsigned short*)d_ws;               // N*D bf16 (scaled)
    unsigned short* zj = zi + (size_t)NROWS * DDIM;           // N*D bf16
    float* pos    = (float*)(zj + (size_t)NROWS * DDIM);      // N
    float* rowsum = pos + NROWS;                              // N
    float* colsum = rowsum + NROWS;                           // N

    // ws is poisoned 0xAA before every timed launch — zero the accumulators.
    hipMemsetAsync(rowsum, 0, 2 * NROWS * sizeof(float), stream);

    normalize_kernel<<<NROWS / 4, 256, 0, stream>>>(emb_i, emb_j, zi, zj, pos);

    dim3 grid(NROWS / BM, NROWS / BN);   // 32 x 32
    gemm_fused_kernel<<<grid, 256, 0, stream>>>(zi, zj, rowsum, colsum);

    finalize_kernel<<<1, 256, 0, stream>>>(pos, rowsum, colsum, (float*)d_out);
}